// Round 2
// baseline (2146.923 us; speedup 1.0000x reference)
//
#include <hip/hip_runtime.h>
#include <hip/hip_bf16.h>
#include <math.h>

#define NN 50000
#define EE 800000
#define DINK 512
#define DHK 128
#define CK 8
#define KIT 5

// logH[i][j] = log_sigmoid(param[i][j] + param[j][i]), 8x8
__global__ __launch_bounds__(64) void logH_kernel(const float* __restrict__ param,
                                                  float* __restrict__ logH) {
    int t = threadIdx.x;
    int i = t >> 3, j = t & 7;
    float z = param[i * 8 + j] + param[j * 8 + i];
    // stable log-sigmoid: min(z,0) - log1p(exp(-|z|))
    logH[t] = fminf(z, 0.0f) - log1pf(expf(-fabsf(z)));
}

// Fused MLP: log_b0 = log_softmax(relu(x@W1+b1)@W2 + b2); also log_b = log_b0.
// Block = 256 threads, tile = 64 nodes x 128 hidden.
// Thread (tx,ty): tx=tid&15 -> j0=tx*8 hidden cols; ty=tid>>4 -> m0=ty*4 nodes.
__global__ __launch_bounds__(256) void mlp_kernel(
    const float* __restrict__ x, const float* __restrict__ W1,
    const float* __restrict__ b1, const float* __restrict__ W2,
    const float* __restrict__ b2, float* __restrict__ logb0,
    float* __restrict__ logb) {
    __shared__ float xs[64][33];   // +1 pad
    __shared__ float ws[32][132];  // stride 132 keeps 16B alignment for float4
    const int tid = threadIdx.x;
    const int tx = tid & 15;
    const int ty = tid >> 4;
    const int n0 = blockIdx.x * 64;
    const int m0 = ty * 4;
    const int j0 = tx * 8;

    float acc[4][8];
#pragma unroll
    for (int i = 0; i < 4; ++i)
#pragma unroll
        for (int j = 0; j < 8; ++j) acc[i][j] = 0.0f;

    for (int k0 = 0; k0 < DINK; k0 += 32) {
        for (int idx = tid; idx < 64 * 32; idx += 256) {
            int r = idx >> 5, c = idx & 31;
            int n = n0 + r;
            xs[r][c] = (n < NN) ? x[(size_t)n * DINK + k0 + c] : 0.0f;
        }
        for (int idx = tid; idx < 32 * 128; idx += 256) {
            int r = idx >> 7, c = idx & 127;
            ws[r][c] = W1[(size_t)(k0 + r) * DHK + c];
        }
        __syncthreads();
#pragma unroll 8
        for (int k = 0; k < 32; ++k) {
            float a0 = xs[m0 + 0][k];
            float a1 = xs[m0 + 1][k];
            float a2 = xs[m0 + 2][k];
            float a3 = xs[m0 + 3][k];
            float4 bv0 = *(const float4*)&ws[k][j0];
            float4 bv1 = *(const float4*)&ws[k][j0 + 4];
            float bb[8] = {bv0.x, bv0.y, bv0.z, bv0.w, bv1.x, bv1.y, bv1.z, bv1.w};
#pragma unroll
            for (int j = 0; j < 8; ++j) {
                acc[0][j] = fmaf(a0, bb[j], acc[0][j]);
                acc[1][j] = fmaf(a1, bb[j], acc[1][j]);
                acc[2][j] = fmaf(a2, bb[j], acc[2][j]);
                acc[3][j] = fmaf(a3, bb[j], acc[3][j]);
            }
        }
        __syncthreads();
    }

    // bias + relu
    float h[4][8];
#pragma unroll
    for (int j = 0; j < 8; ++j) {
        float bj = b1[j0 + j];
#pragma unroll
        for (int i = 0; i < 4; ++i) h[i][j] = fmaxf(acc[i][j] + bj, 0.0f);
    }
    // second GEMM: partial over this thread's 8 hidden dims
    float p[4][8];
#pragma unroll
    for (int i = 0; i < 4; ++i)
#pragma unroll
        for (int c = 0; c < 8; ++c) p[i][c] = 0.0f;
#pragma unroll
    for (int j = 0; j < 8; ++j) {
#pragma unroll
        for (int c = 0; c < 8; ++c) {
            float w2v = W2[(size_t)(j0 + j) * CK + c];
#pragma unroll
            for (int i = 0; i < 4; ++i) p[i][c] = fmaf(h[i][j], w2v, p[i][c]);
        }
    }
    // butterfly-reduce partials across the 16 tx lanes (same ty group)
#pragma unroll
    for (int off = 1; off < 16; off <<= 1) {
#pragma unroll
        for (int i = 0; i < 4; ++i)
#pragma unroll
            for (int c = 0; c < 8; ++c) p[i][c] += __shfl_xor(p[i][c], off, 16);
    }
    if (tx == 0) {
#pragma unroll
        for (int i = 0; i < 4; ++i) {
            int n = n0 + m0 + i;
            if (n >= NN) continue;
            float v[8];
            float mx = -1e30f;
#pragma unroll
            for (int c = 0; c < 8; ++c) {
                v[c] = p[i][c] + b2[c];
                mx = fmaxf(mx, v[c]);
            }
            float s = 0.0f;
#pragma unroll
            for (int c = 0; c < 8; ++c) s += expf(v[c] - mx);
            float ln = mx + logf(s);
#pragma unroll
            for (int c = 0; c < 8; ++c) {
                float o = v[c] - ln;
                logb0[(size_t)n * 8 + c] = o;
                logb[(size_t)n * 8 + c] = o;
            }
        }
    }
}

// One thread per edge: compute normalized message, scatter-add into agg[dst].
__global__ __launch_bounds__(256) void edge_kernel(
    const int* __restrict__ src, const int* __restrict__ dst,
    const float* __restrict__ ew, const int* __restrict__ rv,
    const float* __restrict__ logH, const float* __restrict__ logb,
    const float* __restrict__ msg_prev, float* __restrict__ msg_out,
    float* __restrict__ agg, int first) {
    __shared__ float lH[64];
    if (threadIdx.x < 64) lH[threadIdx.x] = logH[threadIdx.x];
    __syncthreads();
    int e = blockIdx.x * 256 + threadIdx.x;
    if (e >= EE) return;

    int s = src[e];
    int d = dst[e];
    float w = ew[e];

    const float4* pb = (const float4*)&logb[(size_t)s * 8];
    float4 v0 = pb[0], v1 = pb[1];
    float xj[8] = {v0.x, v0.y, v0.z, v0.w, v1.x, v1.y, v1.z, v1.w};
    if (!first) {
        int r = rv[e];
        const float4* pm = (const float4*)&msg_prev[(size_t)r * 8];
        float4 u0 = pm[0], u1 = pm[1];
        xj[0] -= u0.x; xj[1] -= u0.y; xj[2] -= u0.z; xj[3] -= u0.w;
        xj[4] -= u1.x; xj[5] -= u1.y; xj[6] -= u1.z; xj[7] -= u1.w;
    }

    float mg[8];
#pragma unroll
    for (int c2 = 0; c2 < 8; ++c2) {
        float t[8];
        float mx = -1e30f;
#pragma unroll
        for (int c1 = 0; c1 < 8; ++c1) {
            t[c1] = fmaf(w, lH[c1 * 8 + c2], xj[c1]);
            mx = fmaxf(mx, t[c1]);
        }
        float ssum = 0.0f;
#pragma unroll
        for (int c1 = 0; c1 < 8; ++c1) ssum += expf(t[c1] - mx);
        mg[c2] = mx + logf(ssum);
    }
    // normalize over c2
    float mm = -1e30f;
#pragma unroll
    for (int c = 0; c < 8; ++c) mm = fmaxf(mm, mg[c]);
    float se = 0.0f;
#pragma unroll
    for (int c = 0; c < 8; ++c) se += expf(mg[c] - mm);
    float ln = mm + logf(se);
    float fm[8];
#pragma unroll
    for (int c = 0; c < 8; ++c) fm[c] = mg[c] - ln;

    float4 o0 = make_float4(fm[0], fm[1], fm[2], fm[3]);
    float4 o1 = make_float4(fm[4], fm[5], fm[6], fm[7]);
    float4* po = (float4*)&msg_out[(size_t)e * 8];
    po[0] = o0;
    po[1] = o1;

    float* ag = &agg[(size_t)d * 8];
#pragma unroll
    for (int c = 0; c < 8; ++c) atomicAdd(&ag[c], fm[c]);
}

// Per node: log_b = log_normalize(log_b0 + agg); optionally emit output.
__global__ __launch_bounds__(256) void node_kernel(
    const float* __restrict__ logb0, const float* __restrict__ agg,
    float* __restrict__ logb, float* __restrict__ out, int write_out) {
    int n = blockIdx.x * 256 + threadIdx.x;
    if (n >= NN) return;
    const float4* p0 = (const float4*)&logb0[(size_t)n * 8];
    const float4* pa = (const float4*)&agg[(size_t)n * 8];
    float4 a0 = p0[0], a1 = p0[1];
    float4 g0 = pa[0], g1 = pa[1];
    float v[8] = {a0.x + g0.x, a0.y + g0.y, a0.z + g0.z, a0.w + g0.w,
                  a1.x + g1.x, a1.y + g1.y, a1.z + g1.z, a1.w + g1.w};
    float mx = -1e30f;
#pragma unroll
    for (int c = 0; c < 8; ++c) mx = fmaxf(mx, v[c]);
    float s = 0.0f;
#pragma unroll
    for (int c = 0; c < 8; ++c) s += expf(v[c] - mx);
    float ln = mx + logf(s);
#pragma unroll
    for (int c = 0; c < 8; ++c) v[c] -= ln;
    float4* pl = (float4*)&logb[(size_t)n * 8];
    pl[0] = make_float4(v[0], v[1], v[2], v[3]);
    pl[1] = make_float4(v[4], v[5], v[6], v[7]);
    if (write_out) {
        float4* po = (float4*)&out[(size_t)n * 8];
        po[0] = make_float4(v[0], v[1], v[2], v[3]);
        po[1] = make_float4(v[4], v[5], v[6], v[7]);
    }
}

extern "C" void kernel_launch(void* const* d_in, const int* in_sizes, int n_in,
                              void* d_out, int out_size, void* d_ws, size_t ws_size,
                              hipStream_t stream) {
    const float* x = (const float*)d_in[0];
    const int* ei = (const int*)d_in[1];
    const float* ew = (const float*)d_in[2];
    const int* rv = (const int*)d_in[3];
    const float* W1 = (const float*)d_in[4];
    const float* b1 = (const float*)d_in[5];
    const float* W2 = (const float*)d_in[6];
    const float* b2 = (const float*)d_in[7];
    const float* param = (const float*)d_in[8];
    float* out = (float*)d_out;

    const int* src = ei;        // edge_index row 0 = source
    const int* dst = ei + EE;   // edge_index row 1 = target

    float* wsf = (float*)d_ws;
    float* logH = wsf;                    // 64
    float* logb0 = wsf + 64;              // 400000
    float* logb = logb0 + (size_t)NN * 8; // 400000
    float* agg = logb + (size_t)NN * 8;   // 400000
    float* msgA = agg + (size_t)NN * 8;   // 6.4M
    float* msgB = msgA + (size_t)EE * 8;  // 6.4M

    logH_kernel<<<1, 64, 0, stream>>>(param, logH);
    mlp_kernel<<<(NN + 63) / 64, 256, 0, stream>>>(x, W1, b1, W2, b2, logb0, logb);

    for (int it = 0; it < KIT; ++it) {
        hipMemsetAsync(agg, 0, (size_t)NN * 8 * sizeof(float), stream);
        float* cur = (it & 1) ? msgB : msgA;
        float* prev = (it & 1) ? msgA : msgB;
        edge_kernel<<<(EE + 255) / 256, 256, 0, stream>>>(
            src, dst, ew, rv, logH, logb, prev, cur, agg, it == 0 ? 1 : 0);
        node_kernel<<<(NN + 255) / 256, 256, 0, stream>>>(
            logb0, agg, logb, out, it == KIT - 1 ? 1 : 0);
    }
}

// Round 3
// 827.121 us; speedup vs baseline: 2.5957x; 2.5957x over previous
//
#include <hip/hip_runtime.h>
#include <hip/hip_bf16.h>
#include <math.h>

#define NN 50000
#define EE 800000
#define DINK 512
#define DHK 128
#define CK 8
#define KIT 5

// logH[i][j] = log_sigmoid(param[i][j] + param[j][i]), 8x8
__global__ __launch_bounds__(64) void logH_kernel(const float* __restrict__ param,
                                                  float* __restrict__ logH) {
    int t = threadIdx.x;
    int i = t >> 3, j = t & 7;
    float z = param[i * 8 + j] + param[j * 8 + i];
    logH[t] = fminf(z, 0.0f) - log1pf(expf(-fabsf(z)));
}

// Fused MLP: log_b0 = log_softmax(relu(x@W1+b1)@W2 + b2); also log_b = log_b0.
__global__ __launch_bounds__(256) void mlp_kernel(
    const float* __restrict__ x, const float* __restrict__ W1,
    const float* __restrict__ b1, const float* __restrict__ W2,
    const float* __restrict__ b2, float* __restrict__ logb0,
    float* __restrict__ logb) {
    __shared__ float xs[64][33];
    __shared__ float ws[32][132];
    const int tid = threadIdx.x;
    const int tx = tid & 15;
    const int ty = tid >> 4;
    const int n0 = blockIdx.x * 64;
    const int m0 = ty * 4;
    const int j0 = tx * 8;

    float acc[4][8];
#pragma unroll
    for (int i = 0; i < 4; ++i)
#pragma unroll
        for (int j = 0; j < 8; ++j) acc[i][j] = 0.0f;

    for (int k0 = 0; k0 < DINK; k0 += 32) {
        for (int idx = tid; idx < 64 * 32; idx += 256) {
            int r = idx >> 5, c = idx & 31;
            int n = n0 + r;
            xs[r][c] = (n < NN) ? x[(size_t)n * DINK + k0 + c] : 0.0f;
        }
        for (int idx = tid; idx < 32 * 128; idx += 256) {
            int r = idx >> 7, c = idx & 127;
            ws[r][c] = W1[(size_t)(k0 + r) * DHK + c];
        }
        __syncthreads();
#pragma unroll 8
        for (int k = 0; k < 32; ++k) {
            float a0 = xs[m0 + 0][k];
            float a1 = xs[m0 + 1][k];
            float a2 = xs[m0 + 2][k];
            float a3 = xs[m0 + 3][k];
            float4 bv0 = *(const float4*)&ws[k][j0];
            float4 bv1 = *(const float4*)&ws[k][j0 + 4];
            float bb[8] = {bv0.x, bv0.y, bv0.z, bv0.w, bv1.x, bv1.y, bv1.z, bv1.w};
#pragma unroll
            for (int j = 0; j < 8; ++j) {
                acc[0][j] = fmaf(a0, bb[j], acc[0][j]);
                acc[1][j] = fmaf(a1, bb[j], acc[1][j]);
                acc[2][j] = fmaf(a2, bb[j], acc[2][j]);
                acc[3][j] = fmaf(a3, bb[j], acc[3][j]);
            }
        }
        __syncthreads();
    }

    float h[4][8];
#pragma unroll
    for (int j = 0; j < 8; ++j) {
        float bj = b1[j0 + j];
#pragma unroll
        for (int i = 0; i < 4; ++i) h[i][j] = fmaxf(acc[i][j] + bj, 0.0f);
    }
    float p[4][8];
#pragma unroll
    for (int i = 0; i < 4; ++i)
#pragma unroll
        for (int c = 0; c < 8; ++c) p[i][c] = 0.0f;
#pragma unroll
    for (int j = 0; j < 8; ++j) {
#pragma unroll
        for (int c = 0; c < 8; ++c) {
            float w2v = W2[(size_t)(j0 + j) * CK + c];
#pragma unroll
            for (int i = 0; i < 4; ++i) p[i][c] = fmaf(h[i][j], w2v, p[i][c]);
        }
    }
#pragma unroll
    for (int off = 1; off < 16; off <<= 1) {
#pragma unroll
        for (int i = 0; i < 4; ++i)
#pragma unroll
            for (int c = 0; c < 8; ++c) p[i][c] += __shfl_xor(p[i][c], off, 16);
    }
    if (tx == 0) {
#pragma unroll
        for (int i = 0; i < 4; ++i) {
            int n = n0 + m0 + i;
            if (n >= NN) continue;
            float v[8];
            float mx = -1e30f;
#pragma unroll
            for (int c = 0; c < 8; ++c) {
                v[c] = p[i][c] + b2[c];
                mx = fmaxf(mx, v[c]);
            }
            float s = 0.0f;
#pragma unroll
            for (int c = 0; c < 8; ++c) s += expf(v[c] - mx);
            float ln = mx + logf(s);
#pragma unroll
            for (int c = 0; c < 8; ++c) {
                float o = v[c] - ln;
                logb0[(size_t)n * 8 + c] = o;
                logb[(size_t)n * 8 + c] = o;
            }
        }
    }
}

// ---------------- CSR setup kernels ----------------

__global__ __launch_bounds__(256) void deg_kernel(const int* __restrict__ dst,
                                                  int* __restrict__ cnt) {
    int e = blockIdx.x * 256 + threadIdx.x;
    if (e < EE) atomicAdd(&cnt[dst[e]], 1);
}

// Single-block exclusive scan of cnt[0..NN) -> off[0..NN]
__global__ __launch_bounds__(1024) void scan_kernel(const int* __restrict__ cnt,
                                                    int* __restrict__ off) {
    __shared__ int sdata[1024];
    const int t = threadIdx.x;
    const int CH = (NN + 1023) / 1024;  // 49
    const int base = t * CH;
    int local = 0;
    for (int i = 0; i < CH; ++i) {
        int idx = base + i;
        if (idx < NN) local += cnt[idx];
    }
    sdata[t] = local;
    __syncthreads();
    for (int s = 1; s < 1024; s <<= 1) {
        int v = sdata[t];
        int add = (t >= s) ? sdata[t - s] : 0;
        __syncthreads();
        sdata[t] = v + add;
        __syncthreads();
    }
    int run = (t > 0) ? sdata[t - 1] : 0;
    for (int i = 0; i < CH; ++i) {
        int idx = base + i;
        if (idx < NN) {
            off[idx] = run;
            run += cnt[idx];
        }
    }
    if (t == 1023) off[NN] = sdata[1023];
}

// pos[e] = off[dst[e]] + rank; scatter src/w into dst-sorted order
__global__ __launch_bounds__(256) void pos_kernel(
    const int* __restrict__ src, const int* __restrict__ dst,
    const float* __restrict__ ew, const int* __restrict__ off,
    int* __restrict__ cnt, int* __restrict__ pos,
    int* __restrict__ perm_src, float* __restrict__ perm_w) {
    int e = blockIdx.x * 256 + threadIdx.x;
    if (e >= EE) return;
    int d = dst[e];
    int p = off[d] + atomicAdd(&cnt[d], 1);
    pos[e] = p;
    perm_src[p] = src[e];
    perm_w[p] = ew[e];
}

__global__ __launch_bounds__(256) void rvpos_kernel(const int* __restrict__ rv,
                                                    const int* __restrict__ pos,
                                                    int* __restrict__ perm_rvp) {
    int e = blockIdx.x * 256 + threadIdx.x;
    if (e >= EE) return;
    perm_rvp[pos[e]] = pos[rv[e]];
}

// ---------------- hot loop kernels (no atomics) ----------------

__global__ __launch_bounds__(256) void edge_msg_kernel(
    const int* __restrict__ perm_src, const float* __restrict__ perm_w,
    const int* __restrict__ perm_rvp, const float* __restrict__ logH,
    const float* __restrict__ logb, const float* __restrict__ msg_prev,
    float* __restrict__ msg_out, int first) {
    __shared__ float lH[64];
    if (threadIdx.x < 64) lH[threadIdx.x] = logH[threadIdx.x];
    __syncthreads();
    int p = blockIdx.x * 256 + threadIdx.x;
    if (p >= EE) return;

    int s = perm_src[p];
    float w = perm_w[p];

    const float4* pb = (const float4*)&logb[(size_t)s * 8];
    float4 v0 = pb[0], v1 = pb[1];
    float xj[8] = {v0.x, v0.y, v0.z, v0.w, v1.x, v1.y, v1.z, v1.w};
    if (!first) {
        int r = perm_rvp[p];
        const float4* pm = (const float4*)&msg_prev[(size_t)r * 8];
        float4 u0 = pm[0], u1 = pm[1];
        xj[0] -= u0.x; xj[1] -= u0.y; xj[2] -= u0.z; xj[3] -= u0.w;
        xj[4] -= u1.x; xj[5] -= u1.y; xj[6] -= u1.z; xj[7] -= u1.w;
    }

    float mg[8];
#pragma unroll
    for (int c2 = 0; c2 < 8; ++c2) {
        float t[8];
        float mx = -1e30f;
#pragma unroll
        for (int c1 = 0; c1 < 8; ++c1) {
            t[c1] = fmaf(w, lH[c1 * 8 + c2], xj[c1]);
            mx = fmaxf(mx, t[c1]);
        }
        float ssum = 0.0f;
#pragma unroll
        for (int c1 = 0; c1 < 8; ++c1) ssum += expf(t[c1] - mx);
        mg[c2] = mx + logf(ssum);
    }
    float mm = -1e30f;
#pragma unroll
    for (int c = 0; c < 8; ++c) mm = fmaxf(mm, mg[c]);
    float se = 0.0f;
#pragma unroll
    for (int c = 0; c < 8; ++c) se += expf(mg[c] - mm);
    float ln = mm + logf(se);

    float4 o0 = make_float4(mg[0] - ln, mg[1] - ln, mg[2] - ln, mg[3] - ln);
    float4 o1 = make_float4(mg[4] - ln, mg[5] - ln, mg[6] - ln, mg[7] - ln);
    float4* po = (float4*)&msg_out[(size_t)p * 8];
    po[0] = o0;
    po[1] = o1;
}

// 8 threads per node: contiguous-range aggregation + normalize
__global__ __launch_bounds__(256) void node_agg_kernel(
    const float* __restrict__ logb0, const int* __restrict__ off,
    const float* __restrict__ msg, float* __restrict__ logb,
    float* __restrict__ out, int write_out) {
    int t = blockIdx.x * 256 + threadIdx.x;
    int n = t >> 3;
    int c = t & 7;
    if (n >= NN) return;
    int j0 = off[n], j1 = off[n + 1];
    float a = logb0[(size_t)n * 8 + c];
    for (int j = j0; j < j1; ++j) a += msg[(size_t)j * 8 + c];
    float mx = a;
#pragma unroll
    for (int s = 1; s < 8; s <<= 1) mx = fmaxf(mx, __shfl_xor(mx, s, 8));
    float ex = expf(a - mx);
    float sum = ex;
#pragma unroll
    for (int s = 1; s < 8; s <<= 1) sum += __shfl_xor(sum, s, 8);
    float v = a - (mx + logf(sum));
    logb[(size_t)n * 8 + c] = v;
    if (write_out) out[(size_t)n * 8 + c] = v;
}

// ---------------- fallback (round-2 atomic path) ----------------

__global__ __launch_bounds__(256) void edge_kernel_atomic(
    const int* __restrict__ src, const int* __restrict__ dst,
    const float* __restrict__ ew, const int* __restrict__ rv,
    const float* __restrict__ logH, const float* __restrict__ logb,
    const float* __restrict__ msg_prev, float* __restrict__ msg_out,
    float* __restrict__ agg, int first) {
    __shared__ float lH[64];
    if (threadIdx.x < 64) lH[threadIdx.x] = logH[threadIdx.x];
    __syncthreads();
    int e = blockIdx.x * 256 + threadIdx.x;
    if (e >= EE) return;
    int s = src[e];
    int d = dst[e];
    float w = ew[e];
    const float4* pb = (const float4*)&logb[(size_t)s * 8];
    float4 v0 = pb[0], v1 = pb[1];
    float xj[8] = {v0.x, v0.y, v0.z, v0.w, v1.x, v1.y, v1.z, v1.w};
    if (!first) {
        int r = rv[e];
        const float4* pm = (const float4*)&msg_prev[(size_t)r * 8];
        float4 u0 = pm[0], u1 = pm[1];
        xj[0] -= u0.x; xj[1] -= u0.y; xj[2] -= u0.z; xj[3] -= u0.w;
        xj[4] -= u1.x; xj[5] -= u1.y; xj[6] -= u1.z; xj[7] -= u1.w;
    }
    float mg[8];
#pragma unroll
    for (int c2 = 0; c2 < 8; ++c2) {
        float t[8];
        float mx = -1e30f;
#pragma unroll
        for (int c1 = 0; c1 < 8; ++c1) {
            t[c1] = fmaf(w, lH[c1 * 8 + c2], xj[c1]);
            mx = fmaxf(mx, t[c1]);
        }
        float ssum = 0.0f;
#pragma unroll
        for (int c1 = 0; c1 < 8; ++c1) ssum += expf(t[c1] - mx);
        mg[c2] = mx + logf(ssum);
    }
    float mm = -1e30f;
#pragma unroll
    for (int c = 0; c < 8; ++c) mm = fmaxf(mm, mg[c]);
    float se = 0.0f;
#pragma unroll
    for (int c = 0; c < 8; ++c) se += expf(mg[c] - mm);
    float ln = mm + logf(se);
    float fm[8];
#pragma unroll
    for (int c = 0; c < 8; ++c) fm[c] = mg[c] - ln;
    float4* po = (float4*)&msg_out[(size_t)e * 8];
    po[0] = make_float4(fm[0], fm[1], fm[2], fm[3]);
    po[1] = make_float4(fm[4], fm[5], fm[6], fm[7]);
    float* ag = &agg[(size_t)d * 8];
#pragma unroll
    for (int c = 0; c < 8; ++c) atomicAdd(&ag[c], fm[c]);
}

__global__ __launch_bounds__(256) void node_kernel_atomic(
    const float* __restrict__ logb0, const float* __restrict__ agg,
    float* __restrict__ logb, float* __restrict__ out, int write_out) {
    int n = blockIdx.x * 256 + threadIdx.x;
    if (n >= NN) return;
    const float4* p0 = (const float4*)&logb0[(size_t)n * 8];
    const float4* pa = (const float4*)&agg[(size_t)n * 8];
    float4 a0 = p0[0], a1 = p0[1];
    float4 g0 = pa[0], g1 = pa[1];
    float v[8] = {a0.x + g0.x, a0.y + g0.y, a0.z + g0.z, a0.w + g0.w,
                  a1.x + g1.x, a1.y + g1.y, a1.z + g1.z, a1.w + g1.w};
    float mx = -1e30f;
#pragma unroll
    for (int c = 0; c < 8; ++c) mx = fmaxf(mx, v[c]);
    float s = 0.0f;
#pragma unroll
    for (int c = 0; c < 8; ++c) s += expf(v[c] - mx);
    float ln = mx + logf(s);
#pragma unroll
    for (int c = 0; c < 8; ++c) v[c] -= ln;
    float4* pl = (float4*)&logb[(size_t)n * 8];
    pl[0] = make_float4(v[0], v[1], v[2], v[3]);
    pl[1] = make_float4(v[4], v[5], v[6], v[7]);
    if (write_out) {
        float4* po = (float4*)&out[(size_t)n * 8];
        po[0] = make_float4(v[0], v[1], v[2], v[3]);
        po[1] = make_float4(v[4], v[5], v[6], v[7]);
    }
}

extern "C" void kernel_launch(void* const* d_in, const int* in_sizes, int n_in,
                              void* d_out, int out_size, void* d_ws, size_t ws_size,
                              hipStream_t stream) {
    const float* x = (const float*)d_in[0];
    const int* ei = (const int*)d_in[1];
    const float* ew = (const float*)d_in[2];
    const int* rv = (const int*)d_in[3];
    const float* W1 = (const float*)d_in[4];
    const float* b1 = (const float*)d_in[5];
    const float* W2 = (const float*)d_in[6];
    const float* b2 = (const float*)d_in[7];
    const float* param = (const float*)d_in[8];
    float* out = (float*)d_out;

    const int* src = ei;
    const int* dst = ei + EE;

    float* wsf = (float*)d_ws;
    float* logH = wsf;                         // 64
    float* logb0 = logH + 64;                  // 400000
    float* logb = logb0 + (size_t)NN * 8;      // 400000
    float* msgA = logb + (size_t)NN * 8;       // 6.4M
    float* msgB = msgA + (size_t)EE * 8;       // 6.4M
    float* perm_w = msgB + (size_t)EE * 8;     // 800000
    int* off = (int*)(perm_w + EE);            // 50001
    int* perm_src = off + (NN + 1);            // 800000
    int* perm_rvp = perm_src + EE;             // 800000
    // setup-only arrays alias msgB (first written at it=1, after setup done)
    int* pos = (int*)msgB;                     // 800000
    int* cnt = pos + EE;                       // 50000

    size_t need = (size_t)((int*)(perm_rvp + EE) - (int*)d_ws) * sizeof(int);

    logH_kernel<<<1, 64, 0, stream>>>(param, logH);
    mlp_kernel<<<(NN + 63) / 64, 256, 0, stream>>>(x, W1, b1, W2, b2, logb0, logb);

    const int EB = (EE + 255) / 256;

    if (ws_size >= need) {
        // CSR permutation setup (once per launch)
        hipMemsetAsync(cnt, 0, (size_t)NN * sizeof(int), stream);
        deg_kernel<<<EB, 256, 0, stream>>>(dst, cnt);
        scan_kernel<<<1, 1024, 0, stream>>>(cnt, off);
        hipMemsetAsync(cnt, 0, (size_t)NN * sizeof(int), stream);
        pos_kernel<<<EB, 256, 0, stream>>>(src, dst, ew, off, cnt, pos, perm_src, perm_w);
        rvpos_kernel<<<EB, 256, 0, stream>>>(rv, pos, perm_rvp);

        for (int it = 0; it < KIT; ++it) {
            float* cur = (it & 1) ? msgB : msgA;
            float* prev = (it & 1) ? msgA : msgB;
            edge_msg_kernel<<<EB, 256, 0, stream>>>(
                perm_src, perm_w, perm_rvp, logH, logb, prev, cur, it == 0 ? 1 : 0);
            node_agg_kernel<<<(NN * 8 + 255) / 256, 256, 0, stream>>>(
                logb0, off, cur, logb, out, it == KIT - 1 ? 1 : 0);
        }
    } else {
        // fallback: round-2 atomic path (fits in 56.6MB)
        float* agg = msgB + (size_t)EE * 8;  // reuse perm_w slot
        for (int it = 0; it < KIT; ++it) {
            hipMemsetAsync(agg, 0, (size_t)NN * 8 * sizeof(float), stream);
            float* cur = (it & 1) ? msgB : msgA;
            float* prev = (it & 1) ? msgA : msgB;
            edge_kernel_atomic<<<EB, 256, 0, stream>>>(
                src, dst, ew, rv, logH, logb, prev, cur, agg, it == 0 ? 1 : 0);
            node_kernel_atomic<<<(NN + 255) / 256, 256, 0, stream>>>(
                logb0, agg, logb, out, it == KIT - 1 ? 1 : 0);
        }
    }
}

// Round 4
// 607.089 us; speedup vs baseline: 3.5364x; 1.3624x over previous
//
#include <hip/hip_runtime.h>
#include <hip/hip_bf16.h>
#include <math.h>

#define NN 50000
#define EE 800000
#define DINK 512
#define DHK 128
#define CK 8
#define KIT 5

typedef __attribute__((ext_vector_type(8))) short short8;
typedef __attribute__((ext_vector_type(4))) float f32x4;

__device__ __forceinline__ unsigned short f2bf(float f) {
    union { float f; unsigned int u; } v;
    v.f = f;
    unsigned int u = v.u;
    unsigned int r = (u + 0x7FFFu + ((u >> 16) & 1u)) >> 16;  // RNE
    return (unsigned short)r;
}
__device__ __forceinline__ float bfu2f(unsigned int lo16) {
    union { unsigned int u; float f; } v;
    v.u = lo16 << 16;
    return v.f;
}

// logH[i][j] = log_sigmoid(param[i][j] + param[j][i]), 8x8
__global__ __launch_bounds__(64) void logH_kernel(const float* __restrict__ param,
                                                  float* __restrict__ logH) {
    int t = threadIdx.x;
    int i = t >> 3, j = t & 7;
    float z = param[i * 8 + j] + param[j * 8 + i];
    logH[t] = fminf(z, 0.0f) - log1pf(expf(-fabsf(z)));
}

// W1 [512][128] fp32 -> W1t [128][512] bf16
__global__ __launch_bounds__(256) void w1t_kernel(const float* __restrict__ W1,
                                                  unsigned short* __restrict__ W1t) {
    int idx = blockIdx.x * 256 + threadIdx.x;  // 65536
    int n = idx >> 9;
    int k = idx & 511;
    W1t[idx] = f2bf(W1[(size_t)k * DHK + n]);
}

// MFMA MLP: logb0 = logb = log_softmax(relu(x@W1+b1)@W2 + b2)
// block=256 (4 waves 2x2), tile 128 rows x 128 hidden, K-loop direct-from-global.
__global__ __launch_bounds__(256) void mlp_mfma_kernel(
    const float* __restrict__ x, const unsigned short* __restrict__ W1t,
    const float* __restrict__ b1, const float* __restrict__ W2,
    const float* __restrict__ b2, float* __restrict__ logb0,
    float* __restrict__ logb) {
    __shared__ unsigned short hs[128 * 136];  // h tile, bf16, stride 136
    __shared__ float W2s[128 * 8];
    __shared__ float b1s[128];
    __shared__ float b2s[8];

    const int tid = threadIdx.x;
    const int wave = tid >> 6;
    const int lane = tid & 63;
    const int q = lane >> 4;    // quad 0..3
    const int lm = lane & 15;
    const int wm = wave >> 1, wn = wave & 1;
    const int n0 = blockIdx.x * 128;

    if (tid < 128) b1s[tid] = b1[tid];
    if (tid < 8) b2s[tid] = b2[tid];
    {
        int i = tid * 4;
        *(float4*)&W2s[i] = *(const float4*)&W2[i];
    }
    __syncthreads();

    // A-fragment row pointers (clamped for the 50048 tail)
    const float* xptr[4];
#pragma unroll
    for (int mt = 0; mt < 4; ++mt) {
        int r = n0 + wm * 64 + mt * 16 + lm;
        if (r > NN - 1) r = NN - 1;
        xptr[mt] = x + (size_t)r * DINK + q * 8;
    }
    const unsigned short* bptr[4];
#pragma unroll
    for (int nt = 0; nt < 4; ++nt) {
        int c = wn * 64 + nt * 16 + lm;
        bptr[nt] = W1t + (size_t)c * DINK + q * 8;
    }

    f32x4 acc[4][4];
#pragma unroll
    for (int mt = 0; mt < 4; ++mt)
#pragma unroll
        for (int nt = 0; nt < 4; ++nt) acc[mt][nt] = (f32x4){0.f, 0.f, 0.f, 0.f};

    for (int k0 = 0; k0 < DINK; k0 += 32) {
        short8 af[4], bf[4];
#pragma unroll
        for (int mt = 0; mt < 4; ++mt) {
            float4 u0 = *(const float4*)(xptr[mt] + k0);
            float4 u1 = *(const float4*)(xptr[mt] + k0 + 4);
            short8 a;
            a[0] = (short)f2bf(u0.x); a[1] = (short)f2bf(u0.y);
            a[2] = (short)f2bf(u0.z); a[3] = (short)f2bf(u0.w);
            a[4] = (short)f2bf(u1.x); a[5] = (short)f2bf(u1.y);
            a[6] = (short)f2bf(u1.z); a[7] = (short)f2bf(u1.w);
            af[mt] = a;
        }
#pragma unroll
        for (int nt = 0; nt < 4; ++nt) bf[nt] = *(const short8*)(bptr[nt] + k0);
#pragma unroll
        for (int mt = 0; mt < 4; ++mt)
#pragma unroll
            for (int nt = 0; nt < 4; ++nt)
                acc[mt][nt] = __builtin_amdgcn_mfma_f32_16x16x32_bf16(
                    af[mt], bf[nt], acc[mt][nt], 0, 0, 0);
    }

    // bias + relu -> hs (bf16). C/D layout: col=lane&15, row=(lane>>4)*4+reg
#pragma unroll
    for (int nt = 0; nt < 4; ++nt) {
        int j = wn * 64 + nt * 16 + lm;
        float bj = b1s[j];
#pragma unroll
        for (int mt = 0; mt < 4; ++mt) {
            int rbase = wm * 64 + mt * 16 + q * 4;
#pragma unroll
            for (int r = 0; r < 4; ++r) {
                float h = fmaxf(acc[mt][nt][r] + bj, 0.0f);
                hs[(rbase + r) * 136 + j] = f2bf(h);
            }
        }
    }
    __syncthreads();

    // second GEMM (128->8) + log_softmax; 2 threads per row
    int row = tid >> 1;
    int half = tid & 1;
    const unsigned short* hp = &hs[row * 136 + half * 64];
    float p[8] = {0.f, 0.f, 0.f, 0.f, 0.f, 0.f, 0.f, 0.f};
#pragma unroll
    for (int ch = 0; ch < 8; ++ch) {
        uint4 c4 = *(const uint4*)(hp + ch * 8);
        unsigned int uu[4] = {c4.x, c4.y, c4.z, c4.w};
#pragma unroll
        for (int p2 = 0; p2 < 4; ++p2) {
            float h0 = bfu2f(uu[p2] & 0xFFFFu);
            float h1 = bfu2f(uu[p2] >> 16);
            int j = half * 64 + ch * 8 + p2 * 2;
            const float* w0 = &W2s[j * 8];
            const float* w1 = &W2s[(j + 1) * 8];
#pragma unroll
            for (int c = 0; c < 8; ++c) p[c] = fmaf(h0, w0[c], p[c]);
#pragma unroll
            for (int c = 0; c < 8; ++c) p[c] = fmaf(h1, w1[c], p[c]);
        }
    }
#pragma unroll
    for (int c = 0; c < 8; ++c) p[c] += __shfl_xor(p[c], 1, 64);
    int grow = n0 + row;
    if (half == 0 && grow < NN) {
        float v[8];
        float mx = -1e30f;
#pragma unroll
        for (int c = 0; c < 8; ++c) {
            v[c] = p[c] + b2s[c];
            mx = fmaxf(mx, v[c]);
        }
        float s = 0.0f;
#pragma unroll
        for (int c = 0; c < 8; ++c) s += expf(v[c] - mx);
        float ln = mx + logf(s);
        float4 o0 = make_float4(v[0] - ln, v[1] - ln, v[2] - ln, v[3] - ln);
        float4 o1 = make_float4(v[4] - ln, v[5] - ln, v[6] - ln, v[7] - ln);
        float4* p0 = (float4*)&logb0[(size_t)grow * 8];
        p0[0] = o0; p0[1] = o1;
        float4* pl = (float4*)&logb[(size_t)grow * 8];
        pl[0] = o0; pl[1] = o1;
    }
}

// ---------------- CSR setup kernels ----------------

__global__ __launch_bounds__(256) void deg_kernel(const int* __restrict__ dst,
                                                  int* __restrict__ cnt) {
    int e = blockIdx.x * 256 + threadIdx.x;
    if (e < EE) atomicAdd(&cnt[dst[e]], 1);
}

__global__ __launch_bounds__(1024) void scan_kernel(const int* __restrict__ cnt,
                                                    int* __restrict__ off) {
    __shared__ int sdata[1024];
    const int t = threadIdx.x;
    const int CH = (NN + 1023) / 1024;  // 49
    const int base = t * CH;
    int local = 0;
    for (int i = 0; i < CH; ++i) {
        int idx = base + i;
        if (idx < NN) local += cnt[idx];
    }
    sdata[t] = local;
    __syncthreads();
    for (int s = 1; s < 1024; s <<= 1) {
        int v = sdata[t];
        int add = (t >= s) ? sdata[t - s] : 0;
        __syncthreads();
        sdata[t] = v + add;
        __syncthreads();
    }
    int run = (t > 0) ? sdata[t - 1] : 0;
    for (int i = 0; i < CH; ++i) {
        int idx = base + i;
        if (idx < NN) {
            off[idx] = run;
            run += cnt[idx];
        }
    }
    if (t == 1023) off[NN] = sdata[1023];
}

__global__ __launch_bounds__(256) void pos_kernel(
    const int* __restrict__ src, const int* __restrict__ dst,
    const float* __restrict__ ew, const int* __restrict__ off,
    int* __restrict__ cnt, int* __restrict__ pos,
    int* __restrict__ perm_src, float* __restrict__ perm_w) {
    int e = blockIdx.x * 256 + threadIdx.x;
    if (e >= EE) return;
    int d = dst[e];
    int p = off[d] + atomicAdd(&cnt[d], 1);
    pos[e] = p;
    perm_src[p] = src[e];
    perm_w[p] = ew[e];
}

__global__ __launch_bounds__(256) void rvpos_kernel(const int* __restrict__ rv,
                                                    const int* __restrict__ pos,
                                                    int* __restrict__ perm_rvp) {
    int e = blockIdx.x * 256 + threadIdx.x;
    if (e >= EE) return;
    perm_rvp[pos[e]] = pos[rv[e]];
}

// ---------------- hot loop kernels (no atomics) ----------------

__global__ __launch_bounds__(256) void edge_msg_kernel(
    const int* __restrict__ perm_src, const float* __restrict__ perm_w,
    const int* __restrict__ perm_rvp, const float* __restrict__ logH,
    const float* __restrict__ logb, const float* __restrict__ msg_prev,
    float* __restrict__ msg_out, int first) {
    __shared__ float lH[64];
    if (threadIdx.x < 64) lH[threadIdx.x] = logH[threadIdx.x];
    __syncthreads();
    int p = blockIdx.x * 256 + threadIdx.x;
    if (p >= EE) return;

    int s = perm_src[p];
    float w = perm_w[p];

    const float4* pb = (const float4*)&logb[(size_t)s * 8];
    float4 v0 = pb[0], v1 = pb[1];
    float xj[8] = {v0.x, v0.y, v0.z, v0.w, v1.x, v1.y, v1.z, v1.w};
    if (!first) {
        int r = perm_rvp[p];
        const float4* pm = (const float4*)&msg_prev[(size_t)r * 8];
        float4 u0 = pm[0], u1 = pm[1];
        xj[0] -= u0.x; xj[1] -= u0.y; xj[2] -= u0.z; xj[3] -= u0.w;
        xj[4] -= u1.x; xj[5] -= u1.y; xj[6] -= u1.z; xj[7] -= u1.w;
    }

    float mg[8];
#pragma unroll
    for (int c2 = 0; c2 < 8; ++c2) {
        float t[8];
        float mx = -1e30f;
#pragma unroll
        for (int c1 = 0; c1 < 8; ++c1) {
            t[c1] = fmaf(w, lH[c1 * 8 + c2], xj[c1]);
            mx = fmaxf(mx, t[c1]);
        }
        float ssum = 0.0f;
#pragma unroll
        for (int c1 = 0; c1 < 8; ++c1) ssum += expf(t[c1] - mx);
        mg[c2] = mx + logf(ssum);
    }
    float mm = -1e30f;
#pragma unroll
    for (int c = 0; c < 8; ++c) mm = fmaxf(mm, mg[c]);
    float se = 0.0f;
#pragma unroll
    for (int c = 0; c < 8; ++c) se += expf(mg[c] - mm);
    float ln = mm + logf(se);

    float4 o0 = make_float4(mg[0] - ln, mg[1] - ln, mg[2] - ln, mg[3] - ln);
    float4 o1 = make_float4(mg[4] - ln, mg[5] - ln, mg[6] - ln, mg[7] - ln);
    float4* po = (float4*)&msg_out[(size_t)p * 8];
    po[0] = o0;
    po[1] = o1;
}

__global__ __launch_bounds__(256) void node_agg_kernel(
    const float* __restrict__ logb0, const int* __restrict__ off,
    const float* __restrict__ msg, float* __restrict__ logb,
    float* __restrict__ out, int write_out) {
    int t = blockIdx.x * 256 + threadIdx.x;
    int n = t >> 3;
    int c = t & 7;
    if (n >= NN) return;
    int j0 = off[n], j1 = off[n + 1];
    float a = logb0[(size_t)n * 8 + c];
    for (int j = j0; j < j1; ++j) a += msg[(size_t)j * 8 + c];
    float mx = a;
#pragma unroll
    for (int s = 1; s < 8; s <<= 1) mx = fmaxf(mx, __shfl_xor(mx, s, 8));
    float ex = expf(a - mx);
    float sum = ex;
#pragma unroll
    for (int s = 1; s < 8; s <<= 1) sum += __shfl_xor(sum, s, 8);
    float v = a - (mx + logf(sum));
    logb[(size_t)n * 8 + c] = v;
    if (write_out) out[(size_t)n * 8 + c] = v;
}

extern "C" void kernel_launch(void* const* d_in, const int* in_sizes, int n_in,
                              void* d_out, int out_size, void* d_ws, size_t ws_size,
                              hipStream_t stream) {
    const float* x = (const float*)d_in[0];
    const int* ei = (const int*)d_in[1];
    const float* ew = (const float*)d_in[2];
    const int* rv = (const int*)d_in[3];
    const float* W1 = (const float*)d_in[4];
    const float* b1 = (const float*)d_in[5];
    const float* W2 = (const float*)d_in[6];
    const float* b2 = (const float*)d_in[7];
    const float* param = (const float*)d_in[8];
    float* out = (float*)d_out;

    const int* src = ei;
    const int* dst = ei + EE;

    float* wsf = (float*)d_ws;
    float* logH = wsf;                          // 64
    float* logb0 = logH + 64;                   // 400000
    float* logb = logb0 + (size_t)NN * 8;       // 400000
    float* msgA = logb + (size_t)NN * 8;        // 6.4M
    float* msgB = msgA + (size_t)EE * 8;        // 6.4M
    float* perm_w = msgB + (size_t)EE * 8;      // 800000
    int* off = (int*)(perm_w + EE);             // 50001
    int* perm_src = off + (NN + 1);             // 800000
    int* perm_rvp = perm_src + EE;              // 800000
    unsigned short* W1t = (unsigned short*)(perm_rvp + EE);  // 65536 bf16
    // setup-only arrays alias msgB (first written at it=1, after setup done)
    int* pos = (int*)msgB;                      // 800000
    int* cnt = pos + EE;                        // 50000

    logH_kernel<<<1, 64, 0, stream>>>(param, logH);
    w1t_kernel<<<256, 256, 0, stream>>>(W1, W1t);
    mlp_mfma_kernel<<<(NN + 127) / 128, 256, 0, stream>>>(x, W1t, b1, W2, b2,
                                                          logb0, logb);

    const int EB = (EE + 255) / 256;

    // CSR permutation setup (once per launch)
    hipMemsetAsync(cnt, 0, (size_t)NN * sizeof(int), stream);
    deg_kernel<<<EB, 256, 0, stream>>>(dst, cnt);
    scan_kernel<<<1, 1024, 0, stream>>>(cnt, off);
    hipMemsetAsync(cnt, 0, (size_t)NN * sizeof(int), stream);
    pos_kernel<<<EB, 256, 0, stream>>>(src, dst, ew, off, cnt, pos, perm_src, perm_w);
    rvpos_kernel<<<EB, 256, 0, stream>>>(rv, pos, perm_rvp);

    for (int it = 0; it < KIT; ++it) {
        float* cur = (it & 1) ? msgB : msgA;
        float* prev = (it & 1) ? msgA : msgB;
        edge_msg_kernel<<<EB, 256, 0, stream>>>(
            perm_src, perm_w, perm_rvp, logH, logb, prev, cur, it == 0 ? 1 : 0);
        node_agg_kernel<<<(NN * 8 + 255) / 256, 256, 0, stream>>>(
            logb0, off, cur, logb, out, it == KIT - 1 ? 1 : 0);
    }
}

// Round 5
// 522.473 us; speedup vs baseline: 4.1092x; 1.1620x over previous
//
#include <hip/hip_runtime.h>
#include <hip/hip_bf16.h>
#include <math.h>

#define NN 50000
#define EE 800000
#define DINK 512
#define DHK 128
#define CK 8
#define KIT 5
#define NBLKS 196  // ceil(NN/256)

typedef __attribute__((ext_vector_type(8))) short short8;
typedef __attribute__((ext_vector_type(4))) float f32x4;

__device__ __forceinline__ unsigned short f2bf(float f) {
    union { float f; unsigned int u; } v;
    v.f = f;
    unsigned int u = v.u;
    unsigned int r = (u + 0x7FFFu + ((u >> 16) & 1u)) >> 16;  // RNE
    return (unsigned short)r;
}
__device__ __forceinline__ float bfu2f(unsigned int lo16) {
    union { unsigned int u; float f; } v;
    v.u = lo16 << 16;
    return v.f;
}

// logH[i][j] = log_sigmoid(param[i][j] + param[j][i]), 8x8
__global__ __launch_bounds__(64) void logH_kernel(const float* __restrict__ param,
                                                  float* __restrict__ logH) {
    int t = threadIdx.x;
    int i = t >> 3, j = t & 7;
    float z = param[i * 8 + j] + param[j * 8 + i];
    logH[t] = fminf(z, 0.0f) - log1pf(expf(-fabsf(z)));
}

// W1 [512][128] fp32 -> W1t [128][512] bf16
__global__ __launch_bounds__(256) void w1t_kernel(const float* __restrict__ W1,
                                                  unsigned short* __restrict__ W1t) {
    int idx = blockIdx.x * 256 + threadIdx.x;  // 65536
    int n = idx >> 9;
    int k = idx & 511;
    W1t[idx] = f2bf(W1[(size_t)k * DHK + n]);
}

// MFMA MLP: logb0 = logb = log_softmax(relu(x@W1+b1)@W2 + b2)
__global__ __launch_bounds__(256) void mlp_mfma_kernel(
    const float* __restrict__ x, const unsigned short* __restrict__ W1t,
    const float* __restrict__ b1, const float* __restrict__ W2,
    const float* __restrict__ b2, float* __restrict__ logb0,
    float* __restrict__ logb) {
    __shared__ unsigned short hs[128 * 136];
    __shared__ float W2s[128 * 8];
    __shared__ float b1s[128];
    __shared__ float b2s[8];

    const int tid = threadIdx.x;
    const int wave = tid >> 6;
    const int lane = tid & 63;
    const int q = lane >> 4;
    const int lm = lane & 15;
    const int wm = wave >> 1, wn = wave & 1;
    const int n0 = blockIdx.x * 128;

    if (tid < 128) b1s[tid] = b1[tid];
    if (tid < 8) b2s[tid] = b2[tid];
    {
        int i = tid * 4;
        *(float4*)&W2s[i] = *(const float4*)&W2[i];
    }
    __syncthreads();

    const float* xptr[4];
#pragma unroll
    for (int mt = 0; mt < 4; ++mt) {
        int r = n0 + wm * 64 + mt * 16 + lm;
        if (r > NN - 1) r = NN - 1;
        xptr[mt] = x + (size_t)r * DINK + q * 8;
    }
    const unsigned short* bptr[4];
#pragma unroll
    for (int nt = 0; nt < 4; ++nt) {
        int c = wn * 64 + nt * 16 + lm;
        bptr[nt] = W1t + (size_t)c * DINK + q * 8;
    }

    f32x4 acc[4][4];
#pragma unroll
    for (int mt = 0; mt < 4; ++mt)
#pragma unroll
        for (int nt = 0; nt < 4; ++nt) acc[mt][nt] = (f32x4){0.f, 0.f, 0.f, 0.f};

    for (int k0 = 0; k0 < DINK; k0 += 32) {
        short8 af[4], bf[4];
#pragma unroll
        for (int mt = 0; mt < 4; ++mt) {
            float4 u0 = *(const float4*)(xptr[mt] + k0);
            float4 u1 = *(const float4*)(xptr[mt] + k0 + 4);
            short8 a;
            a[0] = (short)f2bf(u0.x); a[1] = (short)f2bf(u0.y);
            a[2] = (short)f2bf(u0.z); a[3] = (short)f2bf(u0.w);
            a[4] = (short)f2bf(u1.x); a[5] = (short)f2bf(u1.y);
            a[6] = (short)f2bf(u1.z); a[7] = (short)f2bf(u1.w);
            af[mt] = a;
        }
#pragma unroll
        for (int nt = 0; nt < 4; ++nt) bf[nt] = *(const short8*)(bptr[nt] + k0);
#pragma unroll
        for (int mt = 0; mt < 4; ++mt)
#pragma unroll
            for (int nt = 0; nt < 4; ++nt)
                acc[mt][nt] = __builtin_amdgcn_mfma_f32_16x16x32_bf16(
                    af[mt], bf[nt], acc[mt][nt], 0, 0, 0);
    }

#pragma unroll
    for (int nt = 0; nt < 4; ++nt) {
        int j = wn * 64 + nt * 16 + lm;
        float bj = b1s[j];
#pragma unroll
        for (int mt = 0; mt < 4; ++mt) {
            int rbase = wm * 64 + mt * 16 + q * 4;
#pragma unroll
            for (int r = 0; r < 4; ++r) {
                float h = fmaxf(acc[mt][nt][r] + bj, 0.0f);
                hs[(rbase + r) * 136 + j] = f2bf(h);
            }
        }
    }
    __syncthreads();

    int row = tid >> 1;
    int half = tid & 1;
    const unsigned short* hp = &hs[row * 136 + half * 64];
    float p[8] = {0.f, 0.f, 0.f, 0.f, 0.f, 0.f, 0.f, 0.f};
#pragma unroll
    for (int ch = 0; ch < 8; ++ch) {
        uint4 c4 = *(const uint4*)(hp + ch * 8);
        unsigned int uu[4] = {c4.x, c4.y, c4.z, c4.w};
#pragma unroll
        for (int p2 = 0; p2 < 4; ++p2) {
            float h0 = bfu2f(uu[p2] & 0xFFFFu);
            float h1 = bfu2f(uu[p2] >> 16);
            int j = half * 64 + ch * 8 + p2 * 2;
            const float* w0 = &W2s[j * 8];
            const float* w1 = &W2s[(j + 1) * 8];
#pragma unroll
            for (int c = 0; c < 8; ++c) p[c] = fmaf(h0, w0[c], p[c]);
#pragma unroll
            for (int c = 0; c < 8; ++c) p[c] = fmaf(h1, w1[c], p[c]);
        }
    }
#pragma unroll
    for (int c = 0; c < 8; ++c) p[c] += __shfl_xor(p[c], 1, 64);
    int grow = n0 + row;
    if (half == 0 && grow < NN) {
        float v[8];
        float mx = -1e30f;
#pragma unroll
        for (int c = 0; c < 8; ++c) {
            v[c] = p[c] + b2s[c];
            mx = fmaxf(mx, v[c]);
        }
        float s = 0.0f;
#pragma unroll
        for (int c = 0; c < 8; ++c) s += expf(v[c] - mx);
        float ln = mx + logf(s);
        float4 o0 = make_float4(v[0] - ln, v[1] - ln, v[2] - ln, v[3] - ln);
        float4 o1 = make_float4(v[4] - ln, v[5] - ln, v[6] - ln, v[7] - ln);
        float4* p0 = (float4*)&logb0[(size_t)grow * 8];
        p0[0] = o0; p0[1] = o1;
        float4* pl = (float4*)&logb[(size_t)grow * 8];
        pl[0] = o0; pl[1] = o1;
    }
}

// ---------------- CSR setup kernels ----------------

__global__ __launch_bounds__(256) void deg_kernel(const int* __restrict__ dst,
                                                  int* __restrict__ cnt) {
    int e = blockIdx.x * 256 + threadIdx.x;
    if (e < EE) atomicAdd(&cnt[dst[e]], 1);
}

// Hierarchical scan, stage 1: per-block (256-elem) sums
__global__ __launch_bounds__(256) void scan_partial_kernel(
    const int* __restrict__ cnt, int* __restrict__ partial) {
    __shared__ int sd[256];
    int t = threadIdx.x;
    int i = blockIdx.x * 256 + t;
    sd[t] = (i < NN) ? cnt[i] : 0;
    __syncthreads();
#pragma unroll
    for (int s = 128; s > 0; s >>= 1) {
        if (t < s) sd[t] += sd[t + s];
        __syncthreads();
    }
    if (t == 0) partial[blockIdx.x] = sd[0];
}

// stage 2: exclusive scan of the 196 partials (one block)
__global__ __launch_bounds__(256) void scan_tops_kernel(
    const int* __restrict__ partial, int* __restrict__ tops) {
    __shared__ int sd[256];
    int t = threadIdx.x;
    sd[t] = (t < NBLKS) ? partial[t] : 0;
    __syncthreads();
#pragma unroll
    for (int s = 1; s < 256; s <<= 1) {
        int a = sd[t];
        int b = (t >= s) ? sd[t - s] : 0;
        __syncthreads();
        sd[t] = a + b;
        __syncthreads();
    }
    if (t < NBLKS) tops[t] = (t > 0) ? sd[t - 1] : 0;
}

// stage 3: per-block exclusive scan + block prefix -> off
__global__ __launch_bounds__(256) void scan_write_kernel(
    const int* __restrict__ cnt, const int* __restrict__ tops,
    int* __restrict__ off) {
    __shared__ int sd[256];
    int t = threadIdx.x;
    int i = blockIdx.x * 256 + t;
    int v = (i < NN) ? cnt[i] : 0;
    sd[t] = v;
    __syncthreads();
#pragma unroll
    for (int s = 1; s < 256; s <<= 1) {
        int a = sd[t];
        int b = (t >= s) ? sd[t - s] : 0;
        __syncthreads();
        sd[t] = a + b;
        __syncthreads();
    }
    if (i < NN) off[i] = tops[blockIdx.x] + sd[t] - v;
    if (i == NN - 1) off[NN] = EE;
}

__global__ __launch_bounds__(256) void pos_kernel(
    const int* __restrict__ src, const int* __restrict__ dst,
    const float* __restrict__ ew, const int* __restrict__ off,
    int* __restrict__ cnt, int* __restrict__ pos,
    int* __restrict__ perm_src, float* __restrict__ perm_w) {
    int e = blockIdx.x * 256 + threadIdx.x;
    if (e >= EE) return;
    int d = dst[e];
    int p = off[d] + atomicAdd(&cnt[d], 1);
    pos[e] = p;
    perm_src[p] = src[e];
    perm_w[p] = ew[e];
}

__global__ __launch_bounds__(256) void rvpos_kernel(const int* __restrict__ rv,
                                                    const int* __restrict__ pos,
                                                    int* __restrict__ perm_rvp) {
    int e = blockIdx.x * 256 + threadIdx.x;
    if (e >= EE) return;
    perm_rvp[pos[e]] = pos[rv[e]];
}

// ---------------- hot loop kernels (no atomics) ----------------

__global__ __launch_bounds__(256) void edge_msg_kernel(
    const int* __restrict__ perm_src, const float* __restrict__ perm_w,
    const int* __restrict__ perm_rvp, const float* __restrict__ logH,
    const float* __restrict__ logb, const float* __restrict__ msg_prev,
    float* __restrict__ msg_out, int first) {
    __shared__ float lH[64];
    if (threadIdx.x < 64) lH[threadIdx.x] = logH[threadIdx.x];
    __syncthreads();
    int p = blockIdx.x * 256 + threadIdx.x;
    if (p >= EE) return;

    int s = perm_src[p];
    float w = perm_w[p];

    const float4* pb = (const float4*)&logb[(size_t)s * 8];
    float4 v0 = pb[0], v1 = pb[1];
    float xj[8] = {v0.x, v0.y, v0.z, v0.w, v1.x, v1.y, v1.z, v1.w};
    if (!first) {
        int r = perm_rvp[p];
        const float4* pm = (const float4*)&msg_prev[(size_t)r * 8];
        float4 u0 = pm[0], u1 = pm[1];
        xj[0] -= u0.x; xj[1] -= u0.y; xj[2] -= u0.z; xj[3] -= u0.w;
        xj[4] -= u1.x; xj[5] -= u1.y; xj[6] -= u1.z; xj[7] -= u1.w;
    }

    float mg[8];
#pragma unroll
    for (int c2 = 0; c2 < 8; ++c2) {
        float t[8];
        float mx = -1e30f;
#pragma unroll
        for (int c1 = 0; c1 < 8; ++c1) {
            t[c1] = fmaf(w, lH[c1 * 8 + c2], xj[c1]);
            mx = fmaxf(mx, t[c1]);
        }
        float ssum = 0.0f;
#pragma unroll
        for (int c1 = 0; c1 < 8; ++c1) ssum += expf(t[c1] - mx);
        mg[c2] = mx + logf(ssum);
    }
    float mm = -1e30f;
#pragma unroll
    for (int c = 0; c < 8; ++c) mm = fmaxf(mm, mg[c]);
    float se = 0.0f;
#pragma unroll
    for (int c = 0; c < 8; ++c) se += expf(mg[c] - mm);
    float ln = mm + logf(se);

    float4 o0 = make_float4(mg[0] - ln, mg[1] - ln, mg[2] - ln, mg[3] - ln);
    float4 o1 = make_float4(mg[4] - ln, mg[5] - ln, mg[6] - ln, mg[7] - ln);
    float4* po = (float4*)&msg_out[(size_t)p * 8];
    po[0] = o0;
    po[1] = o1;
}

__global__ __launch_bounds__(256) void node_agg_kernel(
    const float* __restrict__ logb0, const int* __restrict__ off,
    const float* __restrict__ msg, float* __restrict__ logb,
    float* __restrict__ out, int write_out) {
    int t = blockIdx.x * 256 + threadIdx.x;
    int n = t >> 3;
    int c = t & 7;
    if (n >= NN) return;
    int j0 = off[n], j1 = off[n + 1];
    float a = logb0[(size_t)n * 8 + c];
    for (int j = j0; j < j1; ++j) a += msg[(size_t)j * 8 + c];
    float mx = a;
#pragma unroll
    for (int s = 1; s < 8; s <<= 1) mx = fmaxf(mx, __shfl_xor(mx, s, 8));
    float ex = expf(a - mx);
    float sum = ex;
#pragma unroll
    for (int s = 1; s < 8; s <<= 1) sum += __shfl_xor(sum, s, 8);
    float v = a - (mx + logf(sum));
    logb[(size_t)n * 8 + c] = v;
    if (write_out) out[(size_t)n * 8 + c] = v;
}

extern "C" void kernel_launch(void* const* d_in, const int* in_sizes, int n_in,
                              void* d_out, int out_size, void* d_ws, size_t ws_size,
                              hipStream_t stream) {
    const float* x = (const float*)d_in[0];
    const int* ei = (const int*)d_in[1];
    const float* ew = (const float*)d_in[2];
    const int* rv = (const int*)d_in[3];
    const float* W1 = (const float*)d_in[4];
    const float* b1 = (const float*)d_in[5];
    const float* W2 = (const float*)d_in[6];
    const float* b2 = (const float*)d_in[7];
    const float* param = (const float*)d_in[8];
    float* out = (float*)d_out;

    const int* src = ei;
    const int* dst = ei + EE;

    float* wsf = (float*)d_ws;
    float* logH = wsf;                          // 64
    float* logb0 = logH + 64;                   // 400000
    float* logb = logb0 + (size_t)NN * 8;       // 400000
    float* msgA = logb + (size_t)NN * 8;        // 6.4M
    float* msgB = msgA + (size_t)EE * 8;        // 6.4M
    float* perm_w = msgB + (size_t)EE * 8;      // 800000
    int* off = (int*)(perm_w + EE);             // 50001
    int* perm_src = off + (NN + 1);             // 800000
    int* perm_rvp = perm_src + EE;              // 800000
    unsigned short* W1t = (unsigned short*)(perm_rvp + EE);  // 65536 bf16
    // setup-only arrays alias msgB (first written at it=1, after setup done)
    int* pos = (int*)msgB;                      // 800000
    int* cnt = pos + EE;                        // 50000
    int* partial = cnt + NN;                    // 196
    int* tops = partial + NBLKS;                // 196

    logH_kernel<<<1, 64, 0, stream>>>(param, logH);
    w1t_kernel<<<256, 256, 0, stream>>>(W1, W1t);
    mlp_mfma_kernel<<<(NN + 127) / 128, 256, 0, stream>>>(x, W1t, b1, W2, b2,
                                                          logb0, logb);

    const int EB = (EE + 255) / 256;

    // CSR permutation setup (once per launch)
    hipMemsetAsync(cnt, 0, (size_t)NN * sizeof(int), stream);
    deg_kernel<<<EB, 256, 0, stream>>>(dst, cnt);
    scan_partial_kernel<<<NBLKS, 256, 0, stream>>>(cnt, partial);
    scan_tops_kernel<<<1, 256, 0, stream>>>(partial, tops);
    scan_write_kernel<<<NBLKS, 256, 0, stream>>>(cnt, tops, off);
    hipMemsetAsync(cnt, 0, (size_t)NN * sizeof(int), stream);
    pos_kernel<<<EB, 256, 0, stream>>>(src, dst, ew, off, cnt, pos, perm_src, perm_w);
    rvpos_kernel<<<EB, 256, 0, stream>>>(rv, pos, perm_rvp);

    for (int it = 0; it < KIT; ++it) {
        float* cur = (it & 1) ? msgB : msgA;
        float* prev = (it & 1) ? msgA : msgB;
        edge_msg_kernel<<<EB, 256, 0, stream>>>(
            perm_src, perm_w, perm_rvp, logH, logb, prev, cur, it == 0 ? 1 : 0);
        node_agg_kernel<<<(NN * 8 + 255) / 256, 256, 0, stream>>>(
            logb0, off, cur, logb, out, it == KIT - 1 ? 1 : 0);
    }
}